// Round 1
// baseline (925.367 us; speedup 1.0000x reference)
//
#include <hip/hip_runtime.h>
#include <math.h>

#define BB 4
#define CC 132
#define TT 32
#define NN 64
#define HIDD 256
#define G4 1024
#define CIN 392
#define KK 16

__device__ __forceinline__ float sigm(float x) { return 1.0f / (1.0f + expf(-x)); }

// ---------------------------------------------------------------------------
// Top-k for ALL timesteps (depends only on inputs). grid = B*T, block = 64.
// Bit-faithful distance: mul/add with no fma contraction, stable selection
// (ties -> lower index) == lax.top_k semantics.
// ---------------------------------------------------------------------------
__global__ __launch_bounds__(64) void ktopk(const float* __restrict__ in,
                                            int* __restrict__ idxw,
                                            float* __restrict__ outI) {
    int blk = blockIdx.x;
    int b = blk & 3, t = blk >> 2;
    int tprev = t > 0 ? t - 1 : 0;
    int n = threadIdx.x;
    __shared__ float P[3][NN];
    for (int c = 0; c < 3; ++c)
        P[c][n] = in[((b*CC + c)*TT + tprev)*NN + n];
    __syncthreads();
    float q0 = in[((b*CC + 0)*TT + t)*NN + n];
    float q1 = in[((b*CC + 1)*TT + t)*NN + n];
    float q2 = in[((b*CC + 2)*TT + t)*NN + n];
    float d[NN];
    #pragma unroll
    for (int m = 0; m < NN; ++m) {
        float dx = q0 - P[0][m], dy = q1 - P[1][m], dz = q2 - P[2][m];
        // ((dx*dx + dy*dy) + dz*dz) exactly as np/jax, no fma contraction:
        float s01 = __fadd_rn(__fmul_rn(dx, dx), __fmul_rn(dy, dy));
        d[m] = __fadd_rn(s01, __fmul_rn(dz, dz));
    }
    float lastD = -INFINITY; int lastI = -1;
    int obase  = ((t*BB + b)*NN + n)*KK;   // ws layout [T][B][N][K]
    int obase2 = ((b*TT + t)*NN + n)*KK;   // output layout [B][T][N][K]
    for (int kk = 0; kk < KK; ++kk) {
        float bd = INFINITY; int bi = NN;
        #pragma unroll
        for (int m = 0; m < NN; ++m) {
            bool elig   = (d[m] > lastD) || (d[m] == lastD && m > lastI);
            bool better = elig && ((d[m] < bd) || (d[m] == bd && m < bi));
            if (better) { bd = d[m]; bi = m; }
        }
        lastD = bd; lastI = bi;
        idxw[obase + kk] = bi;
        outI[obase2 + kk] = (float)bi;   // harness reads whole buffer as f32
    }
}

// ---------------------------------------------------------------------------
// XA[t][b][n][g] = sum_{c<132} W[g,c]*x[b,c,t,n] + bias[g]
//                - sum_{c<4} W[g,132+c]*x[b,c,t,n]
// Treated as K=136 GEMM: channels 132..135 re-read pos channels 0..3 with -W.
// grid = T*B*8 (g-tiles of 128), block = 256. Thread tile 4n x 8g.
// ---------------------------------------------------------------------------
__global__ __launch_bounds__(256) void kxa(const float* __restrict__ in,
                                           const float* __restrict__ W,
                                           const float* __restrict__ bias,
                                           float* __restrict__ XA) {
    int blk = blockIdx.x;
    int gt = blk & 7; int tb = blk >> 3;
    int b = tb & 3; int t = tb >> 2;
    int g0 = gt * 128;
    __shared__ float Xs[34][NN];     // [c][n]
    __shared__ float Ws[34][128];    // [c][g] (pre-negated for c>=132)
    int tid = threadIdx.x;
    int tc = tid & 15, tr = tid >> 4;
    int n0 = tr * 4;
    float acc[4][8];
    #pragma unroll
    for (int j = 0; j < 4; ++j)
        #pragma unroll
        for (int i = 0; i < 8; ++i) acc[j][i] = 0.f;

    for (int ch = 0; ch < 4; ++ch) {
        int c0 = ch * 34;
        __syncthreads();
        for (int i = 0; i < 9; ++i) {                 // 34*64 = 2176 floats
            int flat = i*256 + tid;
            if (flat < 34*NN) {
                int cc = flat >> 6, n = flat & 63;
                int c = c0 + cc;
                int cs = (c < CC) ? c : (c - CC);     // pos extension
                Xs[cc][n] = in[((b*CC + cs)*TT + t)*NN + n];
            }
        }
        for (int i = 0; i < 17; ++i) {                // 34*128 = 4352 floats
            int flat = i*256 + tid;
            int cc = flat >> 7, g = flat & 127;
            int c = c0 + cc;
            float w = W[(g0 + g)*CIN + c];
            Ws[cc][g] = (c < CC) ? w : -w;
        }
        __syncthreads();
        for (int cc = 0; cc < 34; ++cc) {
            float4 x  = *(const float4*)&Xs[cc][n0];
            float4 wa = *(const float4*)&Ws[cc][tc*4];
            float4 wb = *(const float4*)&Ws[cc][64 + tc*4];
            float xv[4]  = {x.x, x.y, x.z, x.w};
            float wav[4] = {wa.x, wa.y, wa.z, wa.w};
            float wbv[4] = {wb.x, wb.y, wb.z, wb.w};
            #pragma unroll
            for (int j = 0; j < 4; ++j)
                #pragma unroll
                for (int i = 0; i < 4; ++i) {
                    acc[j][i]   += xv[j] * wav[i];
                    acc[j][4+i] += xv[j] * wbv[i];
                }
        }
    }
    #pragma unroll
    for (int j = 0; j < 4; ++j) {
        int n = n0 + j;
        int base = ((t*BB + b)*NN + n)*G4 + g0;
        #pragma unroll
        for (int i = 0; i < 4; ++i) {
            XA[base + tc*4 + i]      = acc[j][i]   + bias[g0 + tc*4 + i];
            XA[base + 64 + tc*4 + i] = acc[j][4+i] + bias[g0 + 64 + tc*4 + i];
        }
    }
}

// ---------------------------------------------------------------------------
// HP[b][m][g] = sum_{c<256} W[g,136+c]*hprev[b,m,c]
//             + sum_{c<4}  W[g,132+c]*in[b,c,tprev,m]
// grid = 256 (16 g-tiles x 4 m-tiles x 4 b), block = 256. Thread: 1m x 4g.
// ---------------------------------------------------------------------------
__global__ __launch_bounds__(256) void kh(const float* __restrict__ in,
                                          const float* __restrict__ W,
                                          const float* __restrict__ hprev,
                                          float* __restrict__ HP, int tprev) {
    int blk = blockIdx.x;
    int gt = blk & 15; int mt = (blk >> 4) & 3; int b = blk >> 6;
    int g0 = gt * 64; int m0 = mt * 16;
    __shared__ float Hs[64][17];   // [c][m] pad
    __shared__ float Ws[64][66];   // [c][g] pad (2-way max)
    __shared__ float Pp[4][16];    // prev pos [c][m]
    int tid = threadIdx.x;
    int tc = tid & 15, tr = tid >> 4;
    float acc[4] = {0.f, 0.f, 0.f, 0.f};   // g = g0+tc*4+i ; m = m0+tr

    for (int ch = 0; ch < 4; ++ch) {
        int c0 = ch * 64;
        __syncthreads();
        for (int i = 0; i < 4; ++i) {          // 16m x 64c
            int flat = i*256 + tid;
            int ml = flat >> 6, cc2 = flat & 63;
            Hs[cc2][ml] = hprev[(b*NN + m0 + ml)*HIDD + c0 + cc2];
        }
        for (int i = 0; i < 16; ++i) {         // 64c x 64g, coalesced global
            int flat = i*256 + tid;
            int g = flat >> 6, cc2 = flat & 63;
            Ws[cc2][g] = W[(g0 + g)*CIN + 136 + c0 + cc2];
        }
        __syncthreads();
        for (int cc = 0; cc < 64; ++cc) {
            float h = Hs[cc][tr];
            float2 wa = *(const float2*)&Ws[cc][tc*4];
            float2 wb = *(const float2*)&Ws[cc][tc*4 + 2];
            acc[0] += h * wa.x; acc[1] += h * wa.y;
            acc[2] += h * wb.x; acc[3] += h * wb.y;
        }
    }
    __syncthreads();
    if (tid < 64) {
        int c = tid >> 4, ml = tid & 15;
        Pp[c][ml] = in[((b*CC + c)*TT + tprev)*NN + m0 + ml];
    }
    __syncthreads();
    float p0 = Pp[0][tr], p1 = Pp[1][tr], p2 = Pp[2][tr], p3 = Pp[3][tr];
    int hb = (b*NN + m0 + tr)*G4 + g0 + tc*4;
    #pragma unroll
    for (int i = 0; i < 4; ++i) {
        const float* wr = &W[(g0 + tc*4 + i)*CIN + 132];
        float pd = wr[0]*p0 + wr[1]*p1 + wr[2]*p2 + wr[3]*p3;
        HP[hb + i] = acc[i] + pd;
    }
}

// ---------------------------------------------------------------------------
// LSTM cell + max over K. grid = B*N, block = 256 (thread = hid j).
// ---------------------------------------------------------------------------
__global__ __launch_bounds__(256) void kup(const float* __restrict__ XA,
                                           const float* __restrict__ HP,
                                           const int* __restrict__ idxw,
                                           const float* __restrict__ cprev,
                                           float* __restrict__ hnext,
                                           float* __restrict__ cnext,
                                           float* __restrict__ out, int t) {
    int b = blockIdx.x >> 6, n = blockIdx.x & 63;
    int j = threadIdx.x;
    __shared__ int sidx[KK];
    if (j < KK) sidx[j] = idxw[((t*BB + b)*NN + n)*KK + j];
    __syncthreads();
    int xb = ((t*BB + b)*NN + n)*G4 + j;
    float xa0 = XA[xb], xa1 = XA[xb + 256], xa2 = XA[xb + 512], xa3 = XA[xb + 768];
    float hmax = -INFINITY, cmax = -INFINITY;
    for (int k = 0; k < KK; ++k) {
        int m = sidx[k];
        int base = (b*NN + m)*G4 + j;
        float gi = xa0 + HP[base];
        float gf = xa1 + HP[base + 256];
        float go = xa2 + HP[base + 512];
        float gg = xa3 + HP[base + 768];
        float cg = cprev[(b*NN + m)*HIDD + j];
        float ck = sigm(gf)*cg + sigm(gi)*tanhf(gg);
        float hk = sigm(go)*tanhf(ck);
        hmax = fmaxf(hmax, hk);
        cmax = fmaxf(cmax, ck);
    }
    hnext[(b*NN + n)*HIDD + j] = hmax;
    cnext[(b*NN + n)*HIDD + j] = cmax;
    out[((b*HIDD + j)*TT + t)*NN + n] = hmax;
}

// ---------------------------------------------------------------------------
extern "C" void kernel_launch(void* const* d_in, const int* in_sizes, int n_in,
                              void* d_out, int out_size, void* d_ws, size_t ws_size,
                              hipStream_t stream) {
    const float* in   = (const float*)d_in[0];
    // d_in[1] (offsets) is unused by the reference
    const float* W    = (const float*)d_in[2];
    const float* bias = (const float*)d_in[3];
    float* out  = (float*)d_out;
    float* outI = out + (size_t)BB*HIDD*TT*NN;   // indices region (as f32 values)

    float* ws = (float*)d_ws;
    float* XA = ws;                                  // [T][B][N][G4]  8,388,608
    float* HP = XA + (size_t)TT*BB*NN*G4;            // [B][N][G4]       262,144
    float* h0 = HP + (size_t)BB*NN*G4;               // [B][N][HID]
    float* c0 = h0 + BB*NN*HIDD;
    float* h1 = c0 + BB*NN*HIDD;
    float* c1 = h1 + BB*NN*HIDD;
    int*  idxw = (int*)(c1 + BB*NN*HIDD);            // [T][B][N][K]

    // h(-1) = c(-1) = 0 (h0,c0 contiguous)
    hipMemsetAsync(h0, 0, sizeof(float)*2*BB*NN*HIDD, stream);

    ktopk<<<BB*TT, 64, 0, stream>>>(in, idxw, outI);
    kxa<<<TT*BB*8, 256, 0, stream>>>(in, W, bias, XA);

    for (int t = 0; t < TT; ++t) {
        float* hp = (t & 1) ? h1 : h0;
        float* cp = (t & 1) ? c1 : c0;
        float* hn = (t & 1) ? h0 : h1;
        float* cn = (t & 1) ? c0 : c1;
        int tprev = t > 0 ? t - 1 : 0;
        kh<<<256, 256, 0, stream>>>(in, W, hp, HP, tprev);
        kup<<<BB*NN, 256, 0, stream>>>(XA, HP, idxw, cp, hn, cn, out, t);
    }
}